// Round 13
// baseline (383.452 us; speedup 1.0000x reference)
//
#include <hip/hip_runtime.h>
#include <stdint.h>

#define BN 4
#define SEQ 2048
#define DM 1024
#define NH 16
#define HD 64
#define ROWS (BN*SEQ)   // 8192

typedef float  f32x4  __attribute__((ext_vector_type(4)));
typedef __bf16 bf16x8 __attribute__((ext_vector_type(8)));
typedef __bf16 bf16x4 __attribute__((ext_vector_type(4)));

#define QSCALE 0.18033688f   // log2(e)/8 — folded into Q projection epilogue

__device__ inline bf16x8 cvt8(const float* __restrict__ src) {
    float4 x0 = *(const float4*)src;
    float4 x1 = *(const float4*)(src + 4);
    bf16x8 r;
    r[0] = (__bf16)x0.x; r[1] = (__bf16)x0.y; r[2] = (__bf16)x0.z; r[3] = (__bf16)x0.w;
    r[4] = (__bf16)x1.x; r[5] = (__bf16)x1.y; r[6] = (__bf16)x1.z; r[7] = (__bf16)x1.w;
    return r;
}

// async global->LDS, 16B per lane; lds ptr wave-uniform (HW adds lane*16)
__device__ inline void gl_lds16(const void* g, void* l) {
    __builtin_amdgcn_global_load_lds((const __attribute__((address_space(1))) uint32_t*)g,
                                     (__attribute__((address_space(3))) uint32_t*)l, 16, 0, 0);
}

// ---------------- merged casts ----------------
__global__ __launch_bounds__(256) void cast3(
    const float* __restrict__ a0, const float* __restrict__ a1, const float* __restrict__ a2,
    __bf16* __restrict__ o0, __bf16* __restrict__ o1, __bf16* __restrict__ o2, int n8) {
    int t = blockIdx.x * 256 + threadIdx.x;
    if (t >= n8) return;
    const float* in = (blockIdx.y == 0) ? a0 : (blockIdx.y == 1) ? a1 : a2;
    __bf16* out     = (blockIdx.y == 0) ? o0 : (blockIdx.y == 1) ? o1 : o2;
    *(bf16x8*)&out[(size_t)t * 8] = cvt8(&in[(size_t)t * 8]);
}

__global__ __launch_bounds__(256) void cast4(
    const float* __restrict__ a0, const float* __restrict__ a1,
    const float* __restrict__ a2, const float* __restrict__ a3,
    __bf16* __restrict__ o0, __bf16* __restrict__ o1,
    __bf16* __restrict__ o2, __bf16* __restrict__ o3, int n8) {
    int t = blockIdx.x * 256 + threadIdx.x;
    if (t >= n8) return;
    const float* in = (blockIdx.y == 0) ? a0 : (blockIdx.y == 1) ? a1 : (blockIdx.y == 2) ? a2 : a3;
    __bf16* out     = (blockIdx.y == 0) ? o0 : (blockIdx.y == 1) ? o1 : (blockIdx.y == 2) ? o2 : o3;
    *(bf16x8*)&out[(size_t)t * 8] = cvt8(&in[(size_t)t * 8]);
}

// ======================================================================
// FAST PATH GEMMs: bf16 A and B staged via global_load_lds (m97 structure)
// 128x128 tile, BK=32, As/Bs unpadded [128][32].
// ======================================================================
#define GEMM_CORE_GLDS(Xp, Wp)                                                     \
    __shared__ __align__(16) __bf16 As[128 * 32];                                  \
    __shared__ __align__(16) __bf16 Bs[128 * 32];                                  \
    const int tid  = threadIdx.x;                                                  \
    const int lane = tid & 63;                                                     \
    const int wave = tid >> 6;                                                     \
    const int wm = (wave >> 1) * 64;                                               \
    const int wn = (wave & 1) * 64;                                                \
    const int c16 = lane & 15;                                                     \
    const int g8  = (lane >> 4) * 8;                                               \
    const int row0 = blockIdx.x * 128;                                             \
    const int col0 = blockIdx.y * 128;                                             \
    f32x4 acc[4][4] = {};                                                          \
    for (int k0 = 0; k0 < DM; k0 += 32) {                                          \
        __syncthreads();                                                           \
        _Pragma("unroll")                                                          \
        for (int h = 0; h < 2; h++) {                                              \
            int cidx = h * 256 + tid;                                              \
            gl_lds16(&Xp[(size_t)(row0 + (cidx >> 2)) * DM + k0 + (cidx & 3) * 8], \
                     &As[(size_t)(h * 256 + wave * 64) * 8]);                      \
            gl_lds16(&Wp[(size_t)(col0 + (cidx >> 2)) * DM + k0 + (cidx & 3) * 8], \
                     &Bs[(size_t)(h * 256 + wave * 64) * 8]);                      \
        }                                                                          \
        __syncthreads();                                                           \
        bf16x8 a[4], bfr[4];                                                       \
        _Pragma("unroll")                                                          \
        for (int i = 0; i < 4; i++) a[i]   = *(const bf16x8*)&As[(wm + i * 16 + c16) * 32 + g8]; \
        _Pragma("unroll")                                                          \
        for (int i = 0; i < 4; i++) bfr[i] = *(const bf16x8*)&Bs[(wn + i * 16 + c16) * 32 + g8]; \
        _Pragma("unroll")                                                          \
        for (int mi = 0; mi < 4; mi++)                                             \
            _Pragma("unroll")                                                      \
            for (int ni = 0; ni < 4; ni++)                                         \
                acc[mi][ni] = __builtin_amdgcn_mfma_f32_16x16x32_bf16(a[mi], bfr[ni], acc[mi][ni], 0, 0, 0); \
    }

// merged Q/K/V projection: z=0 -> Qp (pre-scaled), z=1 -> Kp, z=2 -> Vt^T
__global__ __launch_bounds__(256) void gemm_qkv_f(
    const __bf16* __restrict__ qb, const __bf16* __restrict__ kb,
    const __bf16* __restrict__ vb,
    const __bf16* __restrict__ wqb, const __bf16* __restrict__ wkb,
    const __bf16* __restrict__ wvb,
    const float* __restrict__ bq, const float* __restrict__ bk,
    const float* __restrict__ bv,
    __bf16* __restrict__ Qp, __bf16* __restrict__ Kp, __bf16* __restrict__ Vt)
{
    const int z = blockIdx.z;
    const __bf16* X = (z == 0) ? qb : (z == 1) ? kb : vb;
    const __bf16* W = (z == 0) ? wqb : (z == 1) ? wkb : wvb;
    const float* bias = (z == 0) ? bq : (z == 1) ? bk : bv;

    GEMM_CORE_GLDS(X, W)

    if (z < 2) {
        __bf16* O = z ? Kp : Qp;
        const float qsc = z ? 1.0f : QSCALE;   // pre-scale Q by log2(e)/8
        #pragma unroll
        for (int mi = 0; mi < 4; mi++) {
            int r0 = row0 + wm + mi * 16 + (lane >> 4) * 4;
            #pragma unroll
            for (int ni = 0; ni < 4; ni++) {
                int col = col0 + wn + ni * 16 + c16;
                float bsv = bias[col];
                int h = col >> 6, d = col & 63;
                #pragma unroll
                for (int i = 0; i < 4; i++) {
                    int r = r0 + i; int b = r >> 11, s = r & 2047;
                    O[((size_t)(b * NH + h) * SEQ + s) * HD + d] = (__bf16)((acc[mi][ni][i] + bsv) * qsc);
                }
            }
        }
    } else {
        #pragma unroll
        for (int mi = 0; mi < 4; mi++) {
            int r0 = row0 + wm + mi * 16 + (lane >> 4) * 4;
            #pragma unroll
            for (int ni = 0; ni < 4; ni++) {
                int col = col0 + wn + ni * 16 + c16;
                float bsv = bias[col];
                int h = col >> 6, d = col & 63;
                int b = r0 >> 11, s0 = r0 & 2047;
                size_t base = ((size_t)((b * NH + h) * HD + d)) * SEQ + s0;
                #pragma unroll
                for (int i = 0; i < 4; i++)
                    Vt[base + i] = (__bf16)(acc[mi][ni][i] + bsv);
            }
        }
    }
}

// FC: 128x64 tile, grid (64,16) = 1024 blocks = 4/CU. Wave: 64x32, acc[4][2].
__global__ __launch_bounds__(256) void gemm_fc_f(
    const __bf16* __restrict__ Xc, const __bf16* __restrict__ Wfb,
    const float* __restrict__ bias, float* __restrict__ out)
{
    __shared__ __align__(16) __bf16 As[128 * 32];
    __shared__ __align__(16) __bf16 Bs[64 * 32];

    const int tid  = threadIdx.x;
    const int lane = tid & 63;
    const int wave = tid >> 6;
    const int wm = (wave >> 1) * 64;
    const int wn = (wave & 1) * 32;
    const int c16 = lane & 15;
    const int g8  = (lane >> 4) * 8;
    const int row0 = blockIdx.x * 128;
    const int col0 = blockIdx.y * 64;

    f32x4 acc[4][2] = {};
    for (int k0 = 0; k0 < DM; k0 += 32) {
        __syncthreads();
        #pragma unroll
        for (int h = 0; h < 2; h++) {
            int cidx = h * 256 + tid;
            gl_lds16(&Xc[(size_t)(row0 + (cidx >> 2)) * DM + k0 + (cidx & 3) * 8],
                     &As[(size_t)(h * 256 + wave * 64) * 8]);
        }
        gl_lds16(&Wfb[(size_t)(col0 + (tid >> 2)) * DM + k0 + (tid & 3) * 8],
                 &Bs[(size_t)(wave * 64) * 8]);
        __syncthreads();

        bf16x8 a[4], bfr[2];
        #pragma unroll
        for (int i = 0; i < 4; i++) a[i]   = *(const bf16x8*)&As[(wm + i * 16 + c16) * 32 + g8];
        #pragma unroll
        for (int i = 0; i < 2; i++) bfr[i] = *(const bf16x8*)&Bs[(wn + i * 16 + c16) * 32 + g8];
        #pragma unroll
        for (int mi = 0; mi < 4; mi++)
            #pragma unroll
            for (int ni = 0; ni < 2; ni++)
                acc[mi][ni] = __builtin_amdgcn_mfma_f32_16x16x32_bf16(a[mi], bfr[ni], acc[mi][ni], 0, 0, 0);
    }

    #pragma unroll
    for (int mi = 0; mi < 4; mi++) {
        int r0 = row0 + wm + mi * 16 + (lane >> 4) * 4;
        #pragma unroll
        for (int ni = 0; ni < 2; ni++) {
            int col = col0 + wn + ni * 16 + c16;
            float bsv = bias[col];
            #pragma unroll
            for (int i = 0; i < 4; i++)
                out[(size_t)(r0 + i) * DM + col] = acc[mi][ni][i] + bsv;
        }
    }
}

// ======================================================================
// FALLBACK GEMMs (known-good, ws = 67 MB)
// ======================================================================
__global__ __launch_bounds__(256) void gemm_qk(
    const __bf16* __restrict__ qb, const __bf16* __restrict__ kb,
    const float* __restrict__ wqf, const float* __restrict__ wkf,
    const float* __restrict__ bq, const float* __restrict__ bk,
    __bf16* __restrict__ Qp, __bf16* __restrict__ Kp)
{
    const int z = blockIdx.z;
    const __bf16* X = z ? kb : qb;
    const float* W  = z ? wkf : wqf;
    const float* bias = z ? bk : bq;
    __bf16* O = z ? Kp : Qp;
    const float qsc = z ? 1.0f : QSCALE;

    __shared__ __align__(16) __bf16 As[128 * 32];
    __shared__ __align__(16) __bf16 Bs[128 * 32];

    const int tid  = threadIdx.x;
    const int lane = tid & 63;
    const int wave = tid >> 6;
    const int wm = (wave >> 1) * 64;
    const int wn = (wave & 1) * 64;
    const int c16 = lane & 15;
    const int g8  = (lane >> 4) * 8;
    const int row0 = blockIdx.x * 128;
    const int col0 = blockIdx.y * 128;
    const int brow = tid >> 1;
    const int bcc  = (tid & 1) * 16;

    f32x4 acc[4][4] = {};
    for (int k0 = 0; k0 < DM; k0 += 32) {
        __syncthreads();
        #pragma unroll
        for (int h = 0; h < 2; h++) {
            int cidx = h * 256 + tid;
            gl_lds16(&X[(size_t)(row0 + (cidx >> 2)) * DM + k0 + (cidx & 3) * 8],
                     &As[(size_t)(h * 256 + wave * 64) * 8]);
        }
        *(bf16x8*)&Bs[brow * 32 + bcc]     = cvt8(&W[(size_t)(col0 + brow) * DM + k0 + bcc]);
        *(bf16x8*)&Bs[brow * 32 + bcc + 8] = cvt8(&W[(size_t)(col0 + brow) * DM + k0 + bcc + 8]);
        __syncthreads();

        bf16x8 a[4], bfr[4];
        #pragma unroll
        for (int i = 0; i < 4; i++) a[i]   = *(const bf16x8*)&As[(wm + i * 16 + c16) * 32 + g8];
        #pragma unroll
        for (int i = 0; i < 4; i++) bfr[i] = *(const bf16x8*)&Bs[(wn + i * 16 + c16) * 32 + g8];
        #pragma unroll
        for (int mi = 0; mi < 4; mi++)
            #pragma unroll
            for (int ni = 0; ni < 4; ni++)
                acc[mi][ni] = __builtin_amdgcn_mfma_f32_16x16x32_bf16(a[mi], bfr[ni], acc[mi][ni], 0, 0, 0);
    }

    #pragma unroll
    for (int mi = 0; mi < 4; mi++) {
        int r0 = row0 + wm + mi * 16 + (lane >> 4) * 4;
        #pragma unroll
        for (int ni = 0; ni < 4; ni++) {
            int col = col0 + wn + ni * 16 + c16;
            float bsv = bias[col];
            int h = col >> 6, d = col & 63;
            #pragma unroll
            for (int i = 0; i < 4; i++) {
                int r = r0 + i; int b = r >> 11, s = r & 2047;
                O[((size_t)(b * NH + h) * SEQ + s) * HD + d] = (__bf16)((acc[mi][ni][i] + bsv) * qsc);
            }
        }
    }
}

__global__ __launch_bounds__(256) void gemm_v(
    const float* __restrict__ vf, const float* __restrict__ wvf,
    const float* __restrict__ bv, __bf16* __restrict__ Vt)
{
    __shared__ __align__(16) __bf16 As[128 * 32];
    __shared__ __align__(16) __bf16 Bs[128 * 32];

    const int tid  = threadIdx.x;
    const int lane = tid & 63;
    const int wave = tid >> 6;
    const int wm = (wave >> 1) * 64;
    const int wn = (wave & 1) * 64;
    const int c16 = lane & 15;
    const int g8  = (lane >> 4) * 8;
    const int row0 = blockIdx.x * 128;
    const int col0 = blockIdx.y * 128;
    const int brow = tid >> 1;
    const int bcc  = (tid & 1) * 16;

    f32x4 acc[4][4] = {};
    for (int k0 = 0; k0 < DM; k0 += 32) {
        __syncthreads();
        *(bf16x8*)&As[brow * 32 + bcc]     = cvt8(&vf[(size_t)(row0 + brow) * DM + k0 + bcc]);
        *(bf16x8*)&As[brow * 32 + bcc + 8] = cvt8(&vf[(size_t)(row0 + brow) * DM + k0 + bcc + 8]);
        *(bf16x8*)&Bs[brow * 32 + bcc]     = cvt8(&wvf[(size_t)(col0 + brow) * DM + k0 + bcc]);
        *(bf16x8*)&Bs[brow * 32 + bcc + 8] = cvt8(&wvf[(size_t)(col0 + brow) * DM + k0 + bcc + 8]);
        __syncthreads();

        bf16x8 a[4], bfr[4];
        #pragma unroll
        for (int i = 0; i < 4; i++) a[i]   = *(const bf16x8*)&As[(wm + i * 16 + c16) * 32 + g8];
        #pragma unroll
        for (int i = 0; i < 4; i++) bfr[i] = *(const bf16x8*)&Bs[(wn + i * 16 + c16) * 32 + g8];
        #pragma unroll
        for (int mi = 0; mi < 4; mi++)
            #pragma unroll
            for (int ni = 0; ni < 4; ni++)
                acc[mi][ni] = __builtin_amdgcn_mfma_f32_16x16x32_bf16(a[mi], bfr[ni], acc[mi][ni], 0, 0, 0);
    }

    #pragma unroll
    for (int mi = 0; mi < 4; mi++) {
        int r0 = row0 + wm + mi * 16 + (lane >> 4) * 4;
        #pragma unroll
        for (int ni = 0; ni < 4; ni++) {
            int col = col0 + wn + ni * 16 + c16;
            float bsv = bv[col];
            int h = col >> 6, d = col & 63;
            int b = r0 >> 11, s0 = r0 & 2047;
            size_t base = ((size_t)((b * NH + h) * HD + d)) * SEQ + s0;
            #pragma unroll
            for (int i = 0; i < 4; i++)
                Vt[base + i] = (__bf16)(acc[mi][ni][i] + bsv);
        }
    }
}

__global__ __launch_bounds__(256) void gemm_fc(
    const __bf16* __restrict__ Xc, const float* __restrict__ Wf,
    const float* __restrict__ bias, float* __restrict__ out)
{
    __shared__ __align__(16) __bf16 As[128 * 32];
    __shared__ __align__(16) __bf16 Bs[128 * 32];

    const int tid  = threadIdx.x;
    const int lane = tid & 63;
    const int wave = tid >> 6;
    const int wm = (wave >> 1) * 64;
    const int wn = (wave & 1) * 64;
    const int c16 = lane & 15;
    const int g8  = (lane >> 4) * 8;
    const int row0 = blockIdx.x * 128;
    const int col0 = blockIdx.y * 128;
    const int brow = tid >> 1;
    const int bcc  = (tid & 1) * 16;

    f32x4 acc[4][4] = {};
    for (int k0 = 0; k0 < DM; k0 += 32) {
        __syncthreads();
        #pragma unroll
        for (int h = 0; h < 2; h++) {
            int cidx = h * 256 + tid;
            gl_lds16(&Xc[(size_t)(row0 + (cidx >> 2)) * DM + k0 + (cidx & 3) * 8],
                     &As[(size_t)(h * 256 + wave * 64) * 8]);
        }
        *(bf16x8*)&Bs[brow * 32 + bcc]     = cvt8(&Wf[(size_t)(col0 + brow) * DM + k0 + bcc]);
        *(bf16x8*)&Bs[brow * 32 + bcc + 8] = cvt8(&Wf[(size_t)(col0 + brow) * DM + k0 + bcc + 8]);
        __syncthreads();

        bf16x8 a[4], bfr[4];
        #pragma unroll
        for (int i = 0; i < 4; i++) a[i]   = *(const bf16x8*)&As[(wm + i * 16 + c16) * 32 + g8];
        #pragma unroll
        for (int i = 0; i < 4; i++) bfr[i] = *(const bf16x8*)&Bs[(wn + i * 16 + c16) * 32 + g8];
        #pragma unroll
        for (int mi = 0; mi < 4; mi++)
            #pragma unroll
            for (int ni = 0; ni < 4; ni++)
                acc[mi][ni] = __builtin_amdgcn_mfma_f32_16x16x32_bf16(a[mi], bfr[ni], acc[mi][ni], 0, 0, 0);
    }

    #pragma unroll
    for (int mi = 0; mi < 4; mi++) {
        int r0 = row0 + wm + mi * 16 + (lane >> 4) * 4;
        #pragma unroll
        for (int ni = 0; ni < 4; ni++) {
            int col = col0 + wn + ni * 16 + c16;
            float bsv = bias[col];
            #pragma unroll
            for (int i = 0; i < 4; i++)
                out[(size_t)(r0 + i) * DM + col] = acc[mi][ni][i] + bsv;
        }
    }
}

// ======================================================================
// flash attention, SOFTWARE-PIPELINED (T15-lite):
// R11 base (16x16 MFMA, 4-wave, QSCALE fold, transposed grid, permuted-k
// PV, dbuf K/V 32KB) with the serial chain broken: at each tile t the
// NEXT tile's QK cluster issues BEFORE softmax(t), so softmax VALU runs
// under QK(t+1)'s matrix-pipe execution and PV(t)+QK(t+1) form one
// MFMA region. K staged 2-deep, V 1-deep; one barrier per tile; every
// buffer overwrite is separated from its last reader by a barrier.
// NOTE: launch_bounds is (256) WITHOUT a min-waves clause — the double
// accumulator set (scA+scB+o+qf ~ 112 VGPR) must not be squeezed under
// the 128-VGPR cap that (256,4) implies (spill / infeasible alloc).
// Occupancy is grid-capped at 4 blocks/CU anyway (1024 blocks).
// grid (B*H, SEQ/128), block 256 = 4 waves; wave owns 32 queries.
// ======================================================================
#define QK_CLUSTER(SC, KSB)                                                        \
    do {                                                                           \
        _Pragma("unroll")                                                          \
        for (int t_ = 0; t_ < 4; t_++) {                                           \
            SC[t_][0] = (f32x4){0.f, 0.f, 0.f, 0.f};                               \
            SC[t_][1] = (f32x4){0.f, 0.f, 0.f, 0.f};                               \
        }                                                                          \
        _Pragma("unroll")                                                          \
        for (int t_ = 0; t_ < 4; t_++) {                                           \
            _Pragma("unroll")                                                      \
            for (int kc = 0; kc < 2; kc++) {                                       \
                bf16x8 kf = *(const bf16x8*)&(KSB)[(t_ * 16 + c16) * 64 + ((kc * 4 + g) ^ sw) * 8]; \
                SC[t_][0] = __builtin_amdgcn_mfma_f32_16x16x32_bf16(kf, qf[0][kc], SC[t_][0], 0, 0, 0); \
                SC[t_][1] = __builtin_amdgcn_mfma_f32_16x16x32_bf16(kf, qf[1][kc], SC[t_][1], 0, 0, 0); \
            }                                                                      \
        }                                                                          \
    } while (0)

#define SOFTMAX_PV(SC, VSB)                                                        \
    do {                                                                           \
        bf16x8 pf[2][2];                                                           \
        _Pragma("unroll")                                                          \
        for (int qs = 0; qs < 2; qs++) {                                           \
            float ps = 0.f;                                                        \
            _Pragma("unroll")                                                      \
            for (int kc = 0; kc < 2; kc++) {                                       \
                bf16x8 pv8;                                                        \
                _Pragma("unroll")                                                  \
                for (int i = 0; i < 4; i++) {                                      \
                    float pv = exp2f(SC[2 * kc][qs][i]);                           \
                    ps += pv; pv8[i] = (__bf16)pv;                                 \
                }                                                                  \
                _Pragma("unroll")                                                  \
                for (int i = 0; i < 4; i++) {                                      \
                    float pv = exp2f(SC[2 * kc + 1][qs][i]);                       \
                    ps += pv; pv8[4 + i] = (__bf16)pv;                             \
                }                                                                  \
                pf[qs][kc] = pv8;                                                  \
            }                                                                      \
            lp[qs] += ps;                                                          \
        }                                                                          \
        _Pragma("unroll")                                                          \
        for (int t_ = 0; t_ < 4; t_++) {                                           \
            _Pragma("unroll")                                                      \
            for (int kc = 0; kc < 2; kc++) {                                       \
                union { bf16x8 v8; bf16x4 v4[2]; } u;                              \
                u.v4[0] = *(const bf16x4*)&(VSB)[(t_ * 16 + c16) * 64 + (((kc * 4 + (g >> 1)) ^ sw) * 8) + (g & 1) * 4]; \
                u.v4[1] = *(const bf16x4*)&(VSB)[(t_ * 16 + c16) * 64 + (((kc * 4 + 2 + (g >> 1)) ^ sw) * 8) + (g & 1) * 4]; \
                o[t_][0] = __builtin_amdgcn_mfma_f32_16x16x32_bf16(u.v8, pf[0][kc], o[t_][0], 0, 0, 0); \
                o[t_][1] = __builtin_amdgcn_mfma_f32_16x16x32_bf16(u.v8, pf[1][kc], o[t_][1], 0, 0, 0); \
            }                                                                      \
        }                                                                          \
    } while (0)

__global__ __launch_bounds__(256) void attn_kernel(
    const __bf16* __restrict__ Qp, const __bf16* __restrict__ Kp,
    const __bf16* __restrict__ Vt, __bf16* __restrict__ ctx)
{
    __shared__ __align__(16) __bf16 Ks[2][64 * 64];     // [key][d], swizzled, dbuf
    __shared__ __align__(16) __bf16 Vs[2][64 * 64];     // [d][key], swizzled, dbuf

    const int tid  = threadIdx.x;
    const int lane = tid & 63;
    const int w    = tid >> 6;
    const int bh   = blockIdx.x;                        // head index (XCD-local)
    const int q0   = blockIdx.y * 128 + w * 32;

    const __bf16* Qb = Qp + (size_t)bh * SEQ * HD;
    const __bf16* Kb = Kp + (size_t)bh * SEQ * HD;
    const __bf16* Vb = Vt + (size_t)bh * HD * SEQ;

    const int c16 = lane & 15;
    const int g   = lane >> 4;
    const int sw  = c16 & 7;    // swizzle key for this lane's frag rows

    // Q as B-fragment of Q^T: lane holds Q[query=c16][k = kc*32 + g*8 + j]
    bf16x8 qf[2][2];
    #pragma unroll
    for (int qs = 0; qs < 2; qs++)
        #pragma unroll
        for (int kc = 0; kc < 2; kc++)
            qf[qs][kc] = *(const bf16x8*)&Qb[(size_t)(q0 + qs * 16 + c16) * HD + kc * 32 + g * 8];

    float lp[2] = {0.f, 0.f};
    f32x4 o[4][2] = {};                 // O^T: row d = t*16+g*4+i, col query = c16
    f32x4 scA[4][2], scB[4][2];         // ping-pong QK accumulators

    // GLDS staging: wave w stages rows w*16 .. w*16+15.
    const int srow = (w * 16) + (lane >> 3);          // +8 for h=1
    const int sj   = (lane & 7) ^ (lane >> 3);        // logical chunk (XOR swizzle)

    auto stageK = [&](int kt, int buf) {
        const int k0 = kt * 64;
        #pragma unroll
        for (int h = 0; h < 2; h++) {
            int r = srow + h * 8;
            gl_lds16(&Kb[(size_t)(k0 + r) * HD + sj * 8], &Ks[buf][(size_t)(w * 16 + h * 8) * 64]);
        }
    };
    auto stageV = [&](int kt, int buf) {
        const int k0 = kt * 64;
        #pragma unroll
        for (int h = 0; h < 2; h++) {
            int r = srow + h * 8;
            gl_lds16(&Vb[(size_t)r * SEQ + k0 + sj * 8], &Vs[buf][(size_t)(w * 16 + h * 8) * 64]);
        }
    };

    const int NT = SEQ / 64;            // 32 (even)
    stageK(0, 0); stageV(0, 0); stageK(1, 1);
    __syncthreads();                    // K0, V0, K1 resident
    QK_CLUSTER(scA, &Ks[0][0]);         // QK(0)

    for (int t = 0; t < NT; t += 2) {
        // ---- even sub-iter: tile t (bufs: K read 1, V read 0) ----
        __syncthreads();                // drains K(t+1)/V(t) stages; all waves past QK(t), PV(t-1)
        if (t + 1 < NT) QK_CLUSTER(scB, &Ks[1][0]);     // QK(t+1)
        if (t + 2 < NT) stageK(t + 2, 0);               // Ks[0]: QK(t) all-past
        if (t + 1 < NT) stageV(t + 1, 1);               // Vs[1]: PV(t-1) all-past
        SOFTMAX_PV(scA, &Vs[0][0]);                     // softmax(t) under QK(t+1); PV(t)

        // ---- odd sub-iter: tile t+1 (bufs: K read 0, V read 1) ----
        __syncthreads();                // drains K(t+2)/V(t+1); all waves past QK(t+1), PV(t)
        if (t + 2 < NT) QK_CLUSTER(scA, &Ks[0][0]);     // QK(t+2)
        if (t + 3 < NT) stageK(t + 3, 1);               // Ks[1]: QK(t+1) all-past
        if (t + 2 < NT) stageV(t + 2, 0);               // Vs[0]: PV(t) all-past
        if (t + 1 < NT) SOFTMAX_PV(scB, &Vs[1][0]);     // softmax(t+1) under QK(t+2); PV(t+1)
    }

    // finalize: reduce l over the 4 g-lanes, normalize, write ctx
    const int hh = bh & (NH - 1);
    const int bb = bh >> 4;
    #pragma unroll
    for (int qs = 0; qs < 2; qs++) {
        float l = lp[qs];
        l += __shfl_xor(l, 16, 64);
        l += __shfl_xor(l, 32, 64);
        float inv = 1.f / l;
        int s = q0 + qs * 16 + c16;
        #pragma unroll
        for (int t = 0; t < 4; t++) {
            bf16x4 ov;
            #pragma unroll
            for (int i = 0; i < 4; i++) ov[i] = (__bf16)(o[t][qs][i] * inv);
            *(bf16x4*)&ctx[((size_t)(bb * SEQ + s)) * DM + hh * HD + t * 16 + g * 4] = ov;
        }
    }
}

// ---------------- launch ----------------
extern "C" void kernel_launch(void* const* d_in, const int* in_sizes, int n_in,
                              void* d_out, int out_size, void* d_ws, size_t ws_size,
                              hipStream_t stream) {
    const float* q    = (const float*)d_in[0];
    const float* k    = (const float*)d_in[1];
    const float* v    = (const float*)d_in[2];
    const float* w_q  = (const float*)d_in[3];
    const float* b_q  = (const float*)d_in[4];
    const float* w_k  = (const float*)d_in[5];
    const float* b_k  = (const float*)d_in[6];
    const float* w_v  = (const float*)d_in[7];
    const float* b_v  = (const float*)d_in[8];
    const float* w_fc = (const float*)d_in[9];
    const float* b_fc = (const float*)d_in[10];
    float* out = (float*)d_out;

    // qb,kb live in d_out (dead before gemm_fc writes it)
    __bf16* qb = (__bf16*)d_out;
    __bf16* kb = qb + (size_t)ROWS * DM;

    char* p = (char*)d_ws;
    auto alloc = [&](size_t bytes) { char* r = p; p += (bytes + 255) & ~(size_t)255; return r; };
    const size_t XSZ = (size_t)ROWS * DM * 2;   // 16.78 MB
    const size_t WSZ = (size_t)DM * DM * 2;     // 2.10 MB

    __bf16* Qp  = (__bf16*)alloc(XSZ);
    __bf16* Kp  = (__bf16*)alloc(XSZ);
    __bf16* Vt  = (__bf16*)alloc(XSZ);
    __bf16* ctx = (__bf16*)alloc(XSZ);

    const size_t base_need = (size_t)(p - (char*)d_ws);
    const size_t fast_need = base_need + 4 * (WSZ + 256);

    const int n8x = ROWS * DM / 8;   // 1,048,576
    const int n8w = DM * DM / 8;     // 131,072

    // vb lives in the ctx region: dead before attn writes ctx, and does NOT
    // alias Qp -> enables the single merged QKV projection launch.
    __bf16* vb = ctx;

    // q,k -> d_out region; v -> ctx region (one merged launch)
    cast3<<<dim3(n8x / 256, 3), 256, 0, stream>>>(q, k, v, qb, kb, vb, n8x);

    if (ws_size >= fast_need) {
        // FAST PATH: bf16 weights in ws, all GEMMs all-GLDS.
        __bf16* wqb  = (__bf16*)alloc(WSZ);
        __bf16* wkb  = (__bf16*)alloc(WSZ);
        __bf16* wvb  = (__bf16*)alloc(WSZ);
        __bf16* wfcb = (__bf16*)alloc(WSZ);

        cast4<<<dim3(n8w / 256, 4), 256, 0, stream>>>(
            w_q, w_k, w_v, w_fc, wqb, wkb, wvb, wfcb, n8w);

        // merged Q/K/V projections: one 1536-block launch (6 blocks/CU)
        gemm_qkv_f<<<dim3(ROWS / 128, DM / 128, 3), 256, 0, stream>>>(
            qb, kb, vb, wqb, wkb, wvb, b_q, b_k, b_v, Qp, Kp, Vt);

        // grid: x = head (XCD-local K/V), y = q-block (128 queries)
        attn_kernel<<<dim3(BN * NH, SEQ / 128), 256, 0, stream>>>(Qp, Kp, Vt, ctx);

        // FC: 128x64 tiles -> 1024 blocks (4/CU)
        gemm_fc_f<<<dim3(ROWS / 128, DM / 64), 256, 0, stream>>>(ctx, wfcb, b_fc, out);
    } else {
        // FALLBACK (67 MB ws)
        gemm_v<<<dim3(ROWS / 128, DM / 128), 256, 0, stream>>>(v, w_v, b_v, Vt);
        gemm_qk<<<dim3(ROWS / 128, DM / 128, 2), 256, 0, stream>>>(
            qb, kb, w_q, w_k, b_q, b_k, Qp, Kp);

        attn_kernel<<<dim3(BN * NH, SEQ / 128), 256, 0, stream>>>(Qp, Kp, Vt, ctx);

        gemm_fc<<<dim3(ROWS / 128, DM / 128), 256, 0, stream>>>(ctx, w_fc, b_fc, out);
    }
}

// Round 14
// 366.243 us; speedup vs baseline: 1.0470x; 1.0470x over previous
//
#include <hip/hip_runtime.h>
#include <stdint.h>

#define BN 4
#define SEQ 2048
#define DM 1024
#define NH 16
#define HD 64
#define ROWS (BN*SEQ)   // 8192
#define LSZ (BN*NH*SEQ) // 131072 l-entries per split

typedef float  f32x4  __attribute__((ext_vector_type(4)));
typedef __bf16 bf16x8 __attribute__((ext_vector_type(8)));
typedef __bf16 bf16x4 __attribute__((ext_vector_type(4)));

#define QSCALE 0.18033688f   // log2(e)/8 — folded into Q projection epilogue

__device__ inline bf16x8 cvt8(const float* __restrict__ src) {
    float4 x0 = *(const float4*)src;
    float4 x1 = *(const float4*)(src + 4);
    bf16x8 r;
    r[0] = (__bf16)x0.x; r[1] = (__bf16)x0.y; r[2] = (__bf16)x0.z; r[3] = (__bf16)x0.w;
    r[4] = (__bf16)x1.x; r[5] = (__bf16)x1.y; r[6] = (__bf16)x1.z; r[7] = (__bf16)x1.w;
    return r;
}

// async global->LDS, 16B per lane; lds ptr wave-uniform (HW adds lane*16)
__device__ inline void gl_lds16(const void* g, void* l) {
    __builtin_amdgcn_global_load_lds((const __attribute__((address_space(1))) uint32_t*)g,
                                     (__attribute__((address_space(3))) uint32_t*)l, 16, 0, 0);
}

// ---------------- merged casts ----------------
__global__ __launch_bounds__(256) void cast3(
    const float* __restrict__ a0, const float* __restrict__ a1, const float* __restrict__ a2,
    __bf16* __restrict__ o0, __bf16* __restrict__ o1, __bf16* __restrict__ o2, int n8) {
    int t = blockIdx.x * 256 + threadIdx.x;
    if (t >= n8) return;
    const float* in = (blockIdx.y == 0) ? a0 : (blockIdx.y == 1) ? a1 : a2;
    __bf16* out     = (blockIdx.y == 0) ? o0 : (blockIdx.y == 1) ? o1 : o2;
    *(bf16x8*)&out[(size_t)t * 8] = cvt8(&in[(size_t)t * 8]);
}

__global__ __launch_bounds__(256) void cast4(
    const float* __restrict__ a0, const float* __restrict__ a1,
    const float* __restrict__ a2, const float* __restrict__ a3,
    __bf16* __restrict__ o0, __bf16* __restrict__ o1,
    __bf16* __restrict__ o2, __bf16* __restrict__ o3, int n8) {
    int t = blockIdx.x * 256 + threadIdx.x;
    if (t >= n8) return;
    const float* in = (blockIdx.y == 0) ? a0 : (blockIdx.y == 1) ? a1 : (blockIdx.y == 2) ? a2 : a3;
    __bf16* out     = (blockIdx.y == 0) ? o0 : (blockIdx.y == 1) ? o1 : (blockIdx.y == 2) ? o2 : o3;
    *(bf16x8*)&out[(size_t)t * 8] = cvt8(&in[(size_t)t * 8]);
}

// ======================================================================
// FAST PATH GEMMs: bf16 A and B staged via global_load_lds (m97 structure)
// 128x128 tile, BK=32, As/Bs unpadded [128][32].
// ======================================================================
#define GEMM_CORE_GLDS(Xp, Wp)                                                     \
    __shared__ __align__(16) __bf16 As[128 * 32];                                  \
    __shared__ __align__(16) __bf16 Bs[128 * 32];                                  \
    const int tid  = threadIdx.x;                                                  \
    const int lane = tid & 63;                                                     \
    const int wave = tid >> 6;                                                     \
    const int wm = (wave >> 1) * 64;                                               \
    const int wn = (wave & 1) * 64;                                                \
    const int c16 = lane & 15;                                                     \
    const int g8  = (lane >> 4) * 8;                                               \
    const int row0 = blockIdx.x * 128;                                             \
    const int col0 = blockIdx.y * 128;                                             \
    f32x4 acc[4][4] = {};                                                          \
    for (int k0 = 0; k0 < DM; k0 += 32) {                                          \
        __syncthreads();                                                           \
        _Pragma("unroll")                                                          \
        for (int h = 0; h < 2; h++) {                                              \
            int cidx = h * 256 + tid;                                              \
            gl_lds16(&Xp[(size_t)(row0 + (cidx >> 2)) * DM + k0 + (cidx & 3) * 8], \
                     &As[(size_t)(h * 256 + wave * 64) * 8]);                      \
            gl_lds16(&Wp[(size_t)(col0 + (cidx >> 2)) * DM + k0 + (cidx & 3) * 8], \
                     &Bs[(size_t)(h * 256 + wave * 64) * 8]);                      \
        }                                                                          \
        __syncthreads();                                                           \
        bf16x8 a[4], bfr[4];                                                       \
        _Pragma("unroll")                                                          \
        for (int i = 0; i < 4; i++) a[i]   = *(const bf16x8*)&As[(wm + i * 16 + c16) * 32 + g8]; \
        _Pragma("unroll")                                                          \
        for (int i = 0; i < 4; i++) bfr[i] = *(const bf16x8*)&Bs[(wn + i * 16 + c16) * 32 + g8]; \
        _Pragma("unroll")                                                          \
        for (int mi = 0; mi < 4; mi++)                                             \
            _Pragma("unroll")                                                      \
            for (int ni = 0; ni < 4; ni++)                                         \
                acc[mi][ni] = __builtin_amdgcn_mfma_f32_16x16x32_bf16(a[mi], bfr[ni], acc[mi][ni], 0, 0, 0); \
    }

// merged Q/K/V projection: z=0 -> Qp (pre-scaled), z=1 -> Kp, z=2 -> Vt^T
__global__ __launch_bounds__(256) void gemm_qkv_f(
    const __bf16* __restrict__ qb, const __bf16* __restrict__ kb,
    const __bf16* __restrict__ vb,
    const __bf16* __restrict__ wqb, const __bf16* __restrict__ wkb,
    const __bf16* __restrict__ wvb,
    const float* __restrict__ bq, const float* __restrict__ bk,
    const float* __restrict__ bv,
    __bf16* __restrict__ Qp, __bf16* __restrict__ Kp, __bf16* __restrict__ Vt)
{
    const int z = blockIdx.z;
    const __bf16* X = (z == 0) ? qb : (z == 1) ? kb : vb;
    const __bf16* W = (z == 0) ? wqb : (z == 1) ? wkb : wvb;
    const float* bias = (z == 0) ? bq : (z == 1) ? bk : bv;

    GEMM_CORE_GLDS(X, W)

    if (z < 2) {
        __bf16* O = z ? Kp : Qp;
        const float qsc = z ? 1.0f : QSCALE;   // pre-scale Q by log2(e)/8
        #pragma unroll
        for (int mi = 0; mi < 4; mi++) {
            int r0 = row0 + wm + mi * 16 + (lane >> 4) * 4;
            #pragma unroll
            for (int ni = 0; ni < 4; ni++) {
                int col = col0 + wn + ni * 16 + c16;
                float bsv = bias[col];
                int h = col >> 6, d = col & 63;
                #pragma unroll
                for (int i = 0; i < 4; i++) {
                    int r = r0 + i; int b = r >> 11, s = r & 2047;
                    O[((size_t)(b * NH + h) * SEQ + s) * HD + d] = (__bf16)((acc[mi][ni][i] + bsv) * qsc);
                }
            }
        }
    } else {
        #pragma unroll
        for (int mi = 0; mi < 4; mi++) {
            int r0 = row0 + wm + mi * 16 + (lane >> 4) * 4;
            #pragma unroll
            for (int ni = 0; ni < 4; ni++) {
                int col = col0 + wn + ni * 16 + c16;
                float bsv = bias[col];
                int h = col >> 6, d = col & 63;
                int b = r0 >> 11, s0 = r0 & 2047;
                size_t base = ((size_t)((b * NH + h) * HD + d)) * SEQ + s0;
                #pragma unroll
                for (int i = 0; i < 4; i++)
                    Vt[base + i] = (__bf16)(acc[mi][ni][i] + bsv);
            }
        }
    }
}

// FC: 128x64 tile, grid (64,16) = 1024 blocks = 4/CU. Wave: 64x32, acc[4][2].
__global__ __launch_bounds__(256) void gemm_fc_f(
    const __bf16* __restrict__ Xc, const __bf16* __restrict__ Wfb,
    const float* __restrict__ bias, float* __restrict__ out)
{
    __shared__ __align__(16) __bf16 As[128 * 32];
    __shared__ __align__(16) __bf16 Bs[64 * 32];

    const int tid  = threadIdx.x;
    const int lane = tid & 63;
    const int wave = tid >> 6;
    const int wm = (wave >> 1) * 64;
    const int wn = (wave & 1) * 32;
    const int c16 = lane & 15;
    const int g8  = (lane >> 4) * 8;
    const int row0 = blockIdx.x * 128;
    const int col0 = blockIdx.y * 64;

    f32x4 acc[4][2] = {};
    for (int k0 = 0; k0 < DM; k0 += 32) {
        __syncthreads();
        #pragma unroll
        for (int h = 0; h < 2; h++) {
            int cidx = h * 256 + tid;
            gl_lds16(&Xc[(size_t)(row0 + (cidx >> 2)) * DM + k0 + (cidx & 3) * 8],
                     &As[(size_t)(h * 256 + wave * 64) * 8]);
        }
        gl_lds16(&Wfb[(size_t)(col0 + (tid >> 2)) * DM + k0 + (tid & 3) * 8],
                 &Bs[(size_t)(wave * 64) * 8]);
        __syncthreads();

        bf16x8 a[4], bfr[2];
        #pragma unroll
        for (int i = 0; i < 4; i++) a[i]   = *(const bf16x8*)&As[(wm + i * 16 + c16) * 32 + g8];
        #pragma unroll
        for (int i = 0; i < 2; i++) bfr[i] = *(const bf16x8*)&Bs[(wn + i * 16 + c16) * 32 + g8];
        #pragma unroll
        for (int mi = 0; mi < 4; mi++)
            #pragma unroll
            for (int ni = 0; ni < 2; ni++)
                acc[mi][ni] = __builtin_amdgcn_mfma_f32_16x16x32_bf16(a[mi], bfr[ni], acc[mi][ni], 0, 0, 0);
    }

    #pragma unroll
    for (int mi = 0; mi < 4; mi++) {
        int r0 = row0 + wm + mi * 16 + (lane >> 4) * 4;
        #pragma unroll
        for (int ni = 0; ni < 2; ni++) {
            int col = col0 + wn + ni * 16 + c16;
            float bsv = bias[col];
            #pragma unroll
            for (int i = 0; i < 4; i++)
                out[(size_t)(r0 + i) * DM + col] = acc[mi][ni][i] + bsv;
        }
    }
}

// ======================================================================
// FALLBACK GEMMs (known-good, ws = 67 MB)
// ======================================================================
__global__ __launch_bounds__(256) void gemm_qk(
    const __bf16* __restrict__ qb, const __bf16* __restrict__ kb,
    const float* __restrict__ wqf, const float* __restrict__ wkf,
    const float* __restrict__ bq, const float* __restrict__ bk,
    __bf16* __restrict__ Qp, __bf16* __restrict__ Kp)
{
    const int z = blockIdx.z;
    const __bf16* X = z ? kb : qb;
    const float* W  = z ? wkf : wqf;
    const float* bias = z ? bk : bq;
    __bf16* O = z ? Kp : Qp;
    const float qsc = z ? 1.0f : QSCALE;

    __shared__ __align__(16) __bf16 As[128 * 32];
    __shared__ __align__(16) __bf16 Bs[128 * 32];

    const int tid  = threadIdx.x;
    const int lane = tid & 63;
    const int wave = tid >> 6;
    const int wm = (wave >> 1) * 64;
    const int wn = (wave & 1) * 64;
    const int c16 = lane & 15;
    const int g8  = (lane >> 4) * 8;
    const int row0 = blockIdx.x * 128;
    const int col0 = blockIdx.y * 128;
    const int brow = tid >> 1;
    const int bcc  = (tid & 1) * 16;

    f32x4 acc[4][4] = {};
    for (int k0 = 0; k0 < DM; k0 += 32) {
        __syncthreads();
        #pragma unroll
        for (int h = 0; h < 2; h++) {
            int cidx = h * 256 + tid;
            gl_lds16(&X[(size_t)(row0 + (cidx >> 2)) * DM + k0 + (cidx & 3) * 8],
                     &As[(size_t)(h * 256 + wave * 64) * 8]);
        }
        *(bf16x8*)&Bs[brow * 32 + bcc]     = cvt8(&W[(size_t)(col0 + brow) * DM + k0 + bcc]);
        *(bf16x8*)&Bs[brow * 32 + bcc + 8] = cvt8(&W[(size_t)(col0 + brow) * DM + k0 + bcc + 8]);
        __syncthreads();

        bf16x8 a[4], bfr[4];
        #pragma unroll
        for (int i = 0; i < 4; i++) a[i]   = *(const bf16x8*)&As[(wm + i * 16 + c16) * 32 + g8];
        #pragma unroll
        for (int i = 0; i < 4; i++) bfr[i] = *(const bf16x8*)&Bs[(wn + i * 16 + c16) * 32 + g8];
        #pragma unroll
        for (int mi = 0; mi < 4; mi++)
            #pragma unroll
            for (int ni = 0; ni < 4; ni++)
                acc[mi][ni] = __builtin_amdgcn_mfma_f32_16x16x32_bf16(a[mi], bfr[ni], acc[mi][ni], 0, 0, 0);
    }

    #pragma unroll
    for (int mi = 0; mi < 4; mi++) {
        int r0 = row0 + wm + mi * 16 + (lane >> 4) * 4;
        #pragma unroll
        for (int ni = 0; ni < 4; ni++) {
            int col = col0 + wn + ni * 16 + c16;
            float bsv = bias[col];
            int h = col >> 6, d = col & 63;
            #pragma unroll
            for (int i = 0; i < 4; i++) {
                int r = r0 + i; int b = r >> 11, s = r & 2047;
                O[((size_t)(b * NH + h) * SEQ + s) * HD + d] = (__bf16)((acc[mi][ni][i] + bsv) * qsc);
            }
        }
    }
}

__global__ __launch_bounds__(256) void gemm_v(
    const float* __restrict__ vf, const float* __restrict__ wvf,
    const float* __restrict__ bv, __bf16* __restrict__ Vt)
{
    __shared__ __align__(16) __bf16 As[128 * 32];
    __shared__ __align__(16) __bf16 Bs[128 * 32];

    const int tid  = threadIdx.x;
    const int lane = tid & 63;
    const int wave = tid >> 6;
    const int wm = (wave >> 1) * 64;
    const int wn = (wave & 1) * 64;
    const int c16 = lane & 15;
    const int g8  = (lane >> 4) * 8;
    const int row0 = blockIdx.x * 128;
    const int col0 = blockIdx.y * 128;
    const int brow = tid >> 1;
    const int bcc  = (tid & 1) * 16;

    f32x4 acc[4][4] = {};
    for (int k0 = 0; k0 < DM; k0 += 32) {
        __syncthreads();
        *(bf16x8*)&As[brow * 32 + bcc]     = cvt8(&vf[(size_t)(row0 + brow) * DM + k0 + bcc]);
        *(bf16x8*)&As[brow * 32 + bcc + 8] = cvt8(&vf[(size_t)(row0 + brow) * DM + k0 + bcc + 8]);
        *(bf16x8*)&Bs[brow * 32 + bcc]     = cvt8(&wvf[(size_t)(col0 + brow) * DM + k0 + bcc]);
        *(bf16x8*)&Bs[brow * 32 + bcc + 8] = cvt8(&wvf[(size_t)(col0 + brow) * DM + k0 + bcc + 8]);
        __syncthreads();

        bf16x8 a[4], bfr[4];
        #pragma unroll
        for (int i = 0; i < 4; i++) a[i]   = *(const bf16x8*)&As[(wm + i * 16 + c16) * 32 + g8];
        #pragma unroll
        for (int i = 0; i < 4; i++) bfr[i] = *(const bf16x8*)&Bs[(wn + i * 16 + c16) * 32 + g8];
        #pragma unroll
        for (int mi = 0; mi < 4; mi++)
            #pragma unroll
            for (int ni = 0; ni < 4; ni++)
                acc[mi][ni] = __builtin_amdgcn_mfma_f32_16x16x32_bf16(a[mi], bfr[ni], acc[mi][ni], 0, 0, 0);
    }

    #pragma unroll
    for (int mi = 0; mi < 4; mi++) {
        int r0 = row0 + wm + mi * 16 + (lane >> 4) * 4;
        #pragma unroll
        for (int ni = 0; ni < 4; ni++) {
            int col = col0 + wn + ni * 16 + c16;
            float bsv = bv[col];
            int h = col >> 6, d = col & 63;
            int b = r0 >> 11, s0 = r0 & 2047;
            size_t base = ((size_t)((b * NH + h) * HD + d)) * SEQ + s0;
            #pragma unroll
            for (int i = 0; i < 4; i++)
                Vt[base + i] = (__bf16)(acc[mi][ni][i] + bsv);
        }
    }
}

__global__ __launch_bounds__(256) void gemm_fc(
    const __bf16* __restrict__ Xc, const float* __restrict__ Wf,
    const float* __restrict__ bias, float* __restrict__ out)
{
    __shared__ __align__(16) __bf16 As[128 * 32];
    __shared__ __align__(16) __bf16 Bs[128 * 32];

    const int tid  = threadIdx.x;
    const int lane = tid & 63;
    const int wave = tid >> 6;
    const int wm = (wave >> 1) * 64;
    const int wn = (wave & 1) * 64;
    const int c16 = lane & 15;
    const int g8  = (lane >> 4) * 8;
    const int row0 = blockIdx.x * 128;
    const int col0 = blockIdx.y * 128;
    const int brow = tid >> 1;
    const int bcc  = (tid & 1) * 16;

    f32x4 acc[4][4] = {};
    for (int k0 = 0; k0 < DM; k0 += 32) {
        __syncthreads();
        #pragma unroll
        for (int h = 0; h < 2; h++) {
            int cidx = h * 256 + tid;
            gl_lds16(&Xc[(size_t)(row0 + (cidx >> 2)) * DM + k0 + (cidx & 3) * 8],
                     &As[(size_t)(h * 256 + wave * 64) * 8]);
        }
        *(bf16x8*)&Bs[brow * 32 + bcc]     = cvt8(&Wf[(size_t)(col0 + brow) * DM + k0 + bcc]);
        *(bf16x8*)&Bs[brow * 32 + bcc + 8] = cvt8(&Wf[(size_t)(col0 + brow) * DM + k0 + bcc + 8]);
        __syncthreads();

        bf16x8 a[4], bfr[4];
        #pragma unroll
        for (int i = 0; i < 4; i++) a[i]   = *(const bf16x8*)&As[(wm + i * 16 + c16) * 32 + g8];
        #pragma unroll
        for (int i = 0; i < 4; i++) bfr[i] = *(const bf16x8*)&Bs[(wn + i * 16 + c16) * 32 + g8];
        #pragma unroll
        for (int mi = 0; mi < 4; mi++)
            #pragma unroll
            for (int ni = 0; ni < 4; ni++)
                acc[mi][ni] = __builtin_amdgcn_mfma_f32_16x16x32_bf16(a[mi], bfr[ni], acc[mi][ni], 0, 0, 0);
    }

    #pragma unroll
    for (int mi = 0; mi < 4; mi++) {
        int r0 = row0 + wm + mi * 16 + (lane >> 4) * 4;
        #pragma unroll
        for (int ni = 0; ni < 4; ni++) {
            int col = col0 + wn + ni * 16 + c16;
            float bsv = bias[col];
            #pragma unroll
            for (int i = 0; i < 4; i++)
                out[(size_t)(r0 + i) * DM + col] = acc[mi][ni][i] + bsv;
        }
    }
}

// ======================================================================
// flash attention core (R9 proven body: 16x16 MFMA, 4-wave, QSCALE fold,
// transposed grid, permuted-k PV contract, 16KB LDS, single-buffered).
// ATTN_BODY(KTLO, KTHI, CO, LS_STORE) — shared by split and non-split.
// ======================================================================
#define ATTN_BODY(KTLO, KTHI)                                                        \
    __shared__ __align__(16) __bf16 Ks[64 * 64];                                     \
    __shared__ __align__(16) __bf16 Vs[64 * 64];                                     \
    const int tid  = threadIdx.x;                                                    \
    const int lane = tid & 63;                                                       \
    const int w    = tid >> 6;                                                       \
    const int bh   = blockIdx.x;                                                     \
    const int q0   = blockIdx.y * 128 + w * 32;                                      \
    const __bf16* Qb = Qp + (size_t)bh * SEQ * HD;                                   \
    const __bf16* Kb = Kp + (size_t)bh * SEQ * HD;                                   \
    const __bf16* Vb = Vt + (size_t)bh * HD * SEQ;                                   \
    const int c16 = lane & 15;                                                       \
    const int g   = lane >> 4;                                                       \
    const int sw  = c16 & 7;                                                         \
    bf16x8 qf[2][2];                                                                 \
    _Pragma("unroll")                                                                \
    for (int qs = 0; qs < 2; qs++)                                                   \
        _Pragma("unroll")                                                            \
        for (int kc = 0; kc < 2; kc++)                                               \
            qf[qs][kc] = *(const bf16x8*)&Qb[(size_t)(q0 + qs * 16 + c16) * HD + kc * 32 + g * 8]; \
    float lp[2] = {0.f, 0.f};                                                        \
    f32x4 o[4][2] = {};                                                              \
    const int srow = (w * 16) + (lane >> 3);                                         \
    const int sj   = (lane & 7) ^ (lane >> 3);                                       \
    for (int kt = (KTLO); kt < (KTHI); kt++) {                                       \
        const int k0 = kt * 64;                                                      \
        __syncthreads();                                                             \
        _Pragma("unroll")                                                            \
        for (int h = 0; h < 2; h++) {                                                \
            int r = srow + h * 8;                                                    \
            gl_lds16(&Kb[(size_t)(k0 + r) * HD + sj * 8], &Ks[(size_t)(w * 16 + h * 8) * 64]); \
            gl_lds16(&Vb[(size_t)r * SEQ + k0 + sj * 8],  &Vs[(size_t)(w * 16 + h * 8) * 64]); \
        }                                                                            \
        __syncthreads();                                                             \
        f32x4 sc[4][2] = {};                                                         \
        _Pragma("unroll")                                                            \
        for (int t = 0; t < 4; t++) {                                                \
            _Pragma("unroll")                                                        \
            for (int kc = 0; kc < 2; kc++) {                                         \
                bf16x8 kf = *(const bf16x8*)&Ks[(t * 16 + c16) * 64 + ((kc * 4 + g) ^ sw) * 8]; \
                sc[t][0] = __builtin_amdgcn_mfma_f32_16x16x32_bf16(kf, qf[0][kc], sc[t][0], 0, 0, 0); \
                sc[t][1] = __builtin_amdgcn_mfma_f32_16x16x32_bf16(kf, qf[1][kc], sc[t][1], 0, 0, 0); \
            }                                                                        \
        }                                                                            \
        bf16x8 pf[2][2];                                                             \
        _Pragma("unroll")                                                            \
        for (int qs = 0; qs < 2; qs++) {                                             \
            float ps = 0.f;                                                          \
            _Pragma("unroll")                                                        \
            for (int kc = 0; kc < 2; kc++) {                                         \
                bf16x8 pv8;                                                          \
                _Pragma("unroll")                                                    \
                for (int i = 0; i < 4; i++) {                                        \
                    float pv = exp2f(sc[2 * kc][qs][i]);                             \
                    ps += pv; pv8[i] = (__bf16)pv;                                   \
                }                                                                    \
                _Pragma("unroll")                                                    \
                for (int i = 0; i < 4; i++) {                                        \
                    float pv = exp2f(sc[2 * kc + 1][qs][i]);                         \
                    ps += pv; pv8[4 + i] = (__bf16)pv;                               \
                }                                                                    \
                pf[qs][kc] = pv8;                                                    \
            }                                                                        \
            lp[qs] += ps;                                                            \
        }                                                                            \
        _Pragma("unroll")                                                            \
        for (int t = 0; t < 4; t++) {                                                \
            _Pragma("unroll")                                                        \
            for (int kc = 0; kc < 2; kc++) {                                         \
                union { bf16x8 v8; bf16x4 v4[2]; } u;                                \
                u.v4[0] = *(const bf16x4*)&Vs[(t * 16 + c16) * 64 + (((kc * 4 + (g >> 1)) ^ sw) * 8) + (g & 1) * 4]; \
                u.v4[1] = *(const bf16x4*)&Vs[(t * 16 + c16) * 64 + (((kc * 4 + 2 + (g >> 1)) ^ sw) * 8) + (g & 1) * 4]; \
                o[t][0] = __builtin_amdgcn_mfma_f32_16x16x32_bf16(u.v8, pf[0][kc], o[t][0], 0, 0, 0); \
                o[t][1] = __builtin_amdgcn_mfma_f32_16x16x32_bf16(u.v8, pf[1][kc], o[t][1], 0, 0, 0); \
            }                                                                        \
        }                                                                            \
    }

// non-split (proven R9 kernel): full KV range, write normalized ctx
__global__ __launch_bounds__(256, 4) void attn_kernel(
    const __bf16* __restrict__ Qp, const __bf16* __restrict__ Kp,
    const __bf16* __restrict__ Vt, __bf16* __restrict__ ctx)
{
    ATTN_BODY(0, SEQ / 64)

    const int hh = bh & (NH - 1);
    const int bb = bh >> 4;
    #pragma unroll
    for (int qs = 0; qs < 2; qs++) {
        float l = lp[qs];
        l += __shfl_xor(l, 16, 64);
        l += __shfl_xor(l, 32, 64);
        float inv = 1.f / l;
        int s = q0 + qs * 16 + c16;
        #pragma unroll
        for (int t = 0; t < 4; t++) {
            bf16x4 ov;
            #pragma unroll
            for (int i = 0; i < 4; i++) ov[i] = (__bf16)(o[t][qs][i] * inv);
            *(bf16x4*)&ctx[((size_t)(bb * SEQ + s)) * DM + hh * HD + t * 16 + g * 4] = ov;
        }
    }
}

// KV-SPLIT (x2): grid (BH, SEQ/128, 2) = 2048 blocks = 8/CU = 32 waves/CU.
// z handles KV tiles [z*16, z*16+16). Writes partially-normalized O_z
// (o/l_z, bf16, bounded O(1)) to c0/c1 and l_z (f32) to lsum.
__global__ __launch_bounds__(256, 4) void attn_split(
    const __bf16* __restrict__ Qp, const __bf16* __restrict__ Kp,
    const __bf16* __restrict__ Vt, __bf16* __restrict__ c0,
    __bf16* __restrict__ c1, float* __restrict__ lsum)
{
    const int z = blockIdx.z;
    const int ktlo = z * (SEQ / 128);          // 16 tiles per split

    ATTN_BODY(ktlo, ktlo + SEQ / 128)

    __bf16* co = z ? c1 : c0;
    float*  ls = lsum + (size_t)z * LSZ;
    const int hh = bh & (NH - 1);
    const int bb = bh >> 4;
    #pragma unroll
    for (int qs = 0; qs < 2; qs++) {
        float l = lp[qs];
        l += __shfl_xor(l, 16, 64);
        l += __shfl_xor(l, 32, 64);
        float inv = 1.f / l;
        int s = q0 + qs * 16 + c16;
        if (g == 0) ls[(size_t)bh * SEQ + s] = l;
        #pragma unroll
        for (int t = 0; t < 4; t++) {
            bf16x4 ov;
            #pragma unroll
            for (int i = 0; i < 4; i++) ov[i] = (__bf16)(o[t][qs][i] * inv);
            *(bf16x4*)&co[((size_t)(bb * SEQ + s)) * DM + hh * HD + t * 16 + g * 4] = ov;
        }
    }
}

// combine: ctx = (O0*l0 + O1*l1)/(l0+l1), in place into c0. Memory-bound.
__global__ __launch_bounds__(256) void attn_combine(
    __bf16* __restrict__ c0, const __bf16* __restrict__ c1,
    const float* __restrict__ lsum)
{
    int t = blockIdx.x * 256 + threadIdx.x;      // 0 .. ROWS*DM/8-1
    size_t r = (size_t)t * 8;
    int bs  = t >> 7;                            // r / DM  (DM=1024, 8 elems/thread)
    int dmo = (t & 127) * 8;                     // r % DM
    int hh = dmo >> 6;
    int bb = bs >> 11, s = bs & 2047;
    int bh = bb * NH + hh;
    float l0 = lsum[(size_t)bh * SEQ + s];
    float l1 = lsum[(size_t)LSZ + (size_t)bh * SEQ + s];
    float inv = 1.f / (l0 + l1);
    float w0 = l0 * inv, w1 = l1 * inv;
    bf16x8 a = *(const bf16x8*)&c0[r];
    bf16x8 b = *(const bf16x8*)&c1[r];
    bf16x8 ov;
    #pragma unroll
    for (int i = 0; i < 8; i++)
        ov[i] = (__bf16)(w0 * (float)a[i] + w1 * (float)b[i]);
    *(bf16x8*)&c0[r] = ov;
}

// ---------------- launch ----------------
extern "C" void kernel_launch(void* const* d_in, const int* in_sizes, int n_in,
                              void* d_out, int out_size, void* d_ws, size_t ws_size,
                              hipStream_t stream) {
    const float* q    = (const float*)d_in[0];
    const float* k    = (const float*)d_in[1];
    const float* v    = (const float*)d_in[2];
    const float* w_q  = (const float*)d_in[3];
    const float* b_q  = (const float*)d_in[4];
    const float* w_k  = (const float*)d_in[5];
    const float* b_k  = (const float*)d_in[6];
    const float* w_v  = (const float*)d_in[7];
    const float* b_v  = (const float*)d_in[8];
    const float* w_fc = (const float*)d_in[9];
    const float* b_fc = (const float*)d_in[10];
    float* out = (float*)d_out;

    // qb,kb live in d_out (dead before gemm_fc writes it)
    __bf16* qb = (__bf16*)d_out;
    __bf16* kb = qb + (size_t)ROWS * DM;

    char* p = (char*)d_ws;
    auto alloc = [&](size_t bytes) { char* r = p; p += (bytes + 255) & ~(size_t)255; return r; };
    const size_t XSZ = (size_t)ROWS * DM * 2;   // 16.78 MB
    const size_t WSZ = (size_t)DM * DM * 2;     // 2.10 MB

    __bf16* Qp  = (__bf16*)alloc(XSZ);
    __bf16* Kp  = (__bf16*)alloc(XSZ);
    __bf16* Vt  = (__bf16*)alloc(XSZ);
    __bf16* ctx = (__bf16*)alloc(XSZ);

    const size_t base_need = (size_t)(p - (char*)d_ws);
    const size_t fast_need  = base_need + 4 * (WSZ + 256);
    const size_t split_need = fast_need + (XSZ + 256) + (2 * LSZ * 4 + 256);

    const int n8x = ROWS * DM / 8;   // 1,048,576
    const int n8w = DM * DM / 8;     // 131,072

    // vb lives in the ctx region: dead before attn writes ctx.
    __bf16* vb = ctx;

    // q,k -> d_out region; v -> ctx region (one merged launch)
    cast3<<<dim3(n8x / 256, 3), 256, 0, stream>>>(q, k, v, qb, kb, vb, n8x);

    if (ws_size >= fast_need) {
        // FAST PATH: bf16 weights in ws, all GEMMs all-GLDS.
        __bf16* wqb  = (__bf16*)alloc(WSZ);
        __bf16* wkb  = (__bf16*)alloc(WSZ);
        __bf16* wvb  = (__bf16*)alloc(WSZ);
        __bf16* wfcb = (__bf16*)alloc(WSZ);

        cast4<<<dim3(n8w / 256, 4), 256, 0, stream>>>(
            w_q, w_k, w_v, w_fc, wqb, wkb, wvb, wfcb, n8w);

        // merged Q/K/V projections: one 1536-block launch (6 blocks/CU)
        gemm_qkv_f<<<dim3(ROWS / 128, DM / 128, 3), 256, 0, stream>>>(
            qb, kb, vb, wqb, wkb, wvb, b_q, b_k, b_v, Qp, Kp, Vt);

        if (ws_size >= split_need) {
            // KV-SPLIT x2: 2048 blocks = 8/CU (32 waves/CU) + combine pass
            __bf16* ctx1 = (__bf16*)alloc(XSZ);
            float*  lsum = (float*)alloc(2 * LSZ * 4);
            attn_split<<<dim3(BN * NH, SEQ / 128, 2), 256, 0, stream>>>(
                Qp, Kp, Vt, ctx, ctx1, lsum);
            attn_combine<<<n8x / 256, 256, 0, stream>>>(ctx, ctx1, lsum);
        } else {
            attn_kernel<<<dim3(BN * NH, SEQ / 128), 256, 0, stream>>>(Qp, Kp, Vt, ctx);
        }

        // FC: 128x64 tiles -> 1024 blocks (4/CU)
        gemm_fc_f<<<dim3(ROWS / 128, DM / 64), 256, 0, stream>>>(ctx, wfcb, b_fc, out);
    } else {
        // FALLBACK (67 MB ws)
        gemm_v<<<dim3(ROWS / 128, DM / 128), 256, 0, stream>>>(v, w_v, b_v, Vt);
        gemm_qk<<<dim3(ROWS / 128, DM / 128, 2), 256, 0, stream>>>(
            qb, kb, w_q, w_k, b_q, b_k, Qp, Kp);

        attn_kernel<<<dim3(BN * NH, SEQ / 128), 256, 0, stream>>>(Qp, Kp, Vt, ctx);

        gemm_fc<<<dim3(ROWS / 128, DM / 128), 256, 0, stream>>>(ctx, w_fc, b_fc, out);
    }
}

// Round 15
// 357.262 us; speedup vs baseline: 1.0733x; 1.0251x over previous
//
#include <hip/hip_runtime.h>
#include <stdint.h>

#define BN 4
#define SEQ 2048
#define DM 1024
#define NH 16
#define HD 64
#define ROWS (BN*SEQ)   // 8192

typedef float  f32x4  __attribute__((ext_vector_type(4)));
typedef __bf16 bf16x8 __attribute__((ext_vector_type(8)));
typedef __bf16 bf16x4 __attribute__((ext_vector_type(4)));

#define QSCALE 0.18033688f   // log2(e)/8 — folded into Q projection epilogue

__device__ inline bf16x8 cvt8(const float* __restrict__ src) {
    float4 x0 = *(const float4*)src;
    float4 x1 = *(const float4*)(src + 4);
    bf16x8 r;
    r[0] = (__bf16)x0.x; r[1] = (__bf16)x0.y; r[2] = (__bf16)x0.z; r[3] = (__bf16)x0.w;
    r[4] = (__bf16)x1.x; r[5] = (__bf16)x1.y; r[6] = (__bf16)x1.z; r[7] = (__bf16)x1.w;
    return r;
}

// async global->LDS, 16B per lane; lds ptr wave-uniform (HW adds lane*16)
__device__ inline void gl_lds16(const void* g, void* l) {
    __builtin_amdgcn_global_load_lds((const __attribute__((address_space(1))) uint32_t*)g,
                                     (__attribute__((address_space(3))) uint32_t*)l, 16, 0, 0);
}

// ---------------- merged casts ----------------
__global__ __launch_bounds__(256) void cast3(
    const float* __restrict__ a0, const float* __restrict__ a1, const float* __restrict__ a2,
    __bf16* __restrict__ o0, __bf16* __restrict__ o1, __bf16* __restrict__ o2, int n8) {
    int t = blockIdx.x * 256 + threadIdx.x;
    if (t >= n8) return;
    const float* in = (blockIdx.y == 0) ? a0 : (blockIdx.y == 1) ? a1 : a2;
    __bf16* out     = (blockIdx.y == 0) ? o0 : (blockIdx.y == 1) ? o1 : o2;
    *(bf16x8*)&out[(size_t)t * 8] = cvt8(&in[(size_t)t * 8]);
}

__global__ __launch_bounds__(256) void cast4(
    const float* __restrict__ a0, const float* __restrict__ a1,
    const float* __restrict__ a2, const float* __restrict__ a3,
    __bf16* __restrict__ o0, __bf16* __restrict__ o1,
    __bf16* __restrict__ o2, __bf16* __restrict__ o3, int n8) {
    int t = blockIdx.x * 256 + threadIdx.x;
    if (t >= n8) return;
    const float* in = (blockIdx.y == 0) ? a0 : (blockIdx.y == 1) ? a1 : (blockIdx.y == 2) ? a2 : a3;
    __bf16* out     = (blockIdx.y == 0) ? o0 : (blockIdx.y == 1) ? o1 : (blockIdx.y == 2) ? o2 : o3;
    *(bf16x8*)&out[(size_t)t * 8] = cvt8(&in[(size_t)t * 8]);
}

// ======================================================================
// FAST PATH GEMMs: bf16 A and B staged via global_load_lds (m97 structure)
// 128x128 tile, BK=32, As/Bs unpadded [128][32].
// ======================================================================
#define GEMM_CORE_GLDS(Xp, Wp)                                                     \
    __shared__ __align__(16) __bf16 As[128 * 32];                                  \
    __shared__ __align__(16) __bf16 Bs[128 * 32];                                  \
    const int tid  = threadIdx.x;                                                  \
    const int lane = tid & 63;                                                     \
    const int wave = tid >> 6;                                                     \
    const int wm = (wave >> 1) * 64;                                               \
    const int wn = (wave & 1) * 64;                                                \
    const int c16 = lane & 15;                                                     \
    const int g8  = (lane >> 4) * 8;                                               \
    const int row0 = blockIdx.x * 128;                                             \
    const int col0 = blockIdx.y * 128;                                             \
    f32x4 acc[4][4] = {};                                                          \
    for (int k0 = 0; k0 < DM; k0 += 32) {                                          \
        __syncthreads();                                                           \
        _Pragma("unroll")                                                          \
        for (int h = 0; h < 2; h++) {                                              \
            int cidx = h * 256 + tid;                                              \
            gl_lds16(&Xp[(size_t)(row0 + (cidx >> 2)) * DM + k0 + (cidx & 3) * 8], \
                     &As[(size_t)(h * 256 + wave * 64) * 8]);                      \
            gl_lds16(&Wp[(size_t)(col0 + (cidx >> 2)) * DM + k0 + (cidx & 3) * 8], \
                     &Bs[(size_t)(h * 256 + wave * 64) * 8]);                      \
        }                                                                          \
        __syncthreads();                                                           \
        bf16x8 a[4], bfr[4];                                                       \
        _Pragma("unroll")                                                          \
        for (int i = 0; i < 4; i++) a[i]   = *(const bf16x8*)&As[(wm + i * 16 + c16) * 32 + g8]; \
        _Pragma("unroll")                                                          \
        for (int i = 0; i < 4; i++) bfr[i] = *(const bf16x8*)&Bs[(wn + i * 16 + c16) * 32 + g8]; \
        _Pragma("unroll")                                                          \
        for (int mi = 0; mi < 4; mi++)                                             \
            _Pragma("unroll")                                                      \
            for (int ni = 0; ni < 4; ni++)                                         \
                acc[mi][ni] = __builtin_amdgcn_mfma_f32_16x16x32_bf16(a[mi], bfr[ni], acc[mi][ni], 0, 0, 0); \
    }

// merged Q/K/V projection: z=0 -> Qp (pre-scaled), z=1 -> Kp, z=2 -> Vt^T
__global__ __launch_bounds__(256) void gemm_qkv_f(
    const __bf16* __restrict__ qb, const __bf16* __restrict__ kb,
    const __bf16* __restrict__ vb,
    const __bf16* __restrict__ wqb, const __bf16* __restrict__ wkb,
    const __bf16* __restrict__ wvb,
    const float* __restrict__ bq, const float* __restrict__ bk,
    const float* __restrict__ bv,
    __bf16* __restrict__ Qp, __bf16* __restrict__ Kp, __bf16* __restrict__ Vt)
{
    const int z = blockIdx.z;
    const __bf16* X = (z == 0) ? qb : (z == 1) ? kb : vb;
    const __bf16* W = (z == 0) ? wqb : (z == 1) ? wkb : wvb;
    const float* bias = (z == 0) ? bq : (z == 1) ? bk : bv;

    GEMM_CORE_GLDS(X, W)

    if (z < 2) {
        __bf16* O = z ? Kp : Qp;
        const float qsc = z ? 1.0f : QSCALE;   // pre-scale Q by log2(e)/8
        #pragma unroll
        for (int mi = 0; mi < 4; mi++) {
            int r0 = row0 + wm + mi * 16 + (lane >> 4) * 4;
            #pragma unroll
            for (int ni = 0; ni < 4; ni++) {
                int col = col0 + wn + ni * 16 + c16;
                float bsv = bias[col];
                int h = col >> 6, d = col & 63;
                #pragma unroll
                for (int i = 0; i < 4; i++) {
                    int r = r0 + i; int b = r >> 11, s = r & 2047;
                    O[((size_t)(b * NH + h) * SEQ + s) * HD + d] = (__bf16)((acc[mi][ni][i] + bsv) * qsc);
                }
            }
        }
    } else {
        #pragma unroll
        for (int mi = 0; mi < 4; mi++) {
            int r0 = row0 + wm + mi * 16 + (lane >> 4) * 4;
            #pragma unroll
            for (int ni = 0; ni < 4; ni++) {
                int col = col0 + wn + ni * 16 + c16;
                float bsv = bias[col];
                int h = col >> 6, d = col & 63;
                int b = r0 >> 11, s0 = r0 & 2047;
                size_t base = ((size_t)((b * NH + h) * HD + d)) * SEQ + s0;
                #pragma unroll
                for (int i = 0; i < 4; i++)
                    Vt[base + i] = (__bf16)(acc[mi][ni][i] + bsv);
            }
        }
    }
}

// FC: 128x64 tile, grid (64,16) = 1024 blocks = 4/CU. Wave: 64x32, acc[4][2].
__global__ __launch_bounds__(256) void gemm_fc_f(
    const __bf16* __restrict__ Xc, const __bf16* __restrict__ Wfb,
    const float* __restrict__ bias, float* __restrict__ out)
{
    __shared__ __align__(16) __bf16 As[128 * 32];
    __shared__ __align__(16) __bf16 Bs[64 * 32];

    const int tid  = threadIdx.x;
    const int lane = tid & 63;
    const int wave = tid >> 6;
    const int wm = (wave >> 1) * 64;
    const int wn = (wave & 1) * 32;
    const int c16 = lane & 15;
    const int g8  = (lane >> 4) * 8;
    const int row0 = blockIdx.x * 128;
    const int col0 = blockIdx.y * 64;

    f32x4 acc[4][2] = {};
    for (int k0 = 0; k0 < DM; k0 += 32) {
        __syncthreads();
        #pragma unroll
        for (int h = 0; h < 2; h++) {
            int cidx = h * 256 + tid;
            gl_lds16(&Xc[(size_t)(row0 + (cidx >> 2)) * DM + k0 + (cidx & 3) * 8],
                     &As[(size_t)(h * 256 + wave * 64) * 8]);
        }
        gl_lds16(&Wfb[(size_t)(col0 + (tid >> 2)) * DM + k0 + (tid & 3) * 8],
                 &Bs[(size_t)(wave * 64) * 8]);
        __syncthreads();

        bf16x8 a[4], bfr[2];
        #pragma unroll
        for (int i = 0; i < 4; i++) a[i]   = *(const bf16x8*)&As[(wm + i * 16 + c16) * 32 + g8];
        #pragma unroll
        for (int i = 0; i < 2; i++) bfr[i] = *(const bf16x8*)&Bs[(wn + i * 16 + c16) * 32 + g8];
        #pragma unroll
        for (int mi = 0; mi < 4; mi++)
            #pragma unroll
            for (int ni = 0; ni < 2; ni++)
                acc[mi][ni] = __builtin_amdgcn_mfma_f32_16x16x32_bf16(a[mi], bfr[ni], acc[mi][ni], 0, 0, 0);
    }

    #pragma unroll
    for (int mi = 0; mi < 4; mi++) {
        int r0 = row0 + wm + mi * 16 + (lane >> 4) * 4;
        #pragma unroll
        for (int ni = 0; ni < 2; ni++) {
            int col = col0 + wn + ni * 16 + c16;
            float bsv = bias[col];
            #pragma unroll
            for (int i = 0; i < 4; i++)
                out[(size_t)(r0 + i) * DM + col] = acc[mi][ni][i] + bsv;
        }
    }
}

// ======================================================================
// FALLBACK GEMMs (known-good, ws = 67 MB)
// ======================================================================
__global__ __launch_bounds__(256) void gemm_qk(
    const __bf16* __restrict__ qb, const __bf16* __restrict__ kb,
    const float* __restrict__ wqf, const float* __restrict__ wkf,
    const float* __restrict__ bq, const float* __restrict__ bk,
    __bf16* __restrict__ Qp, __bf16* __restrict__ Kp)
{
    const int z = blockIdx.z;
    const __bf16* X = z ? kb : qb;
    const float* W  = z ? wkf : wqf;
    const float* bias = z ? bk : bq;
    __bf16* O = z ? Kp : Qp;
    const float qsc = z ? 1.0f : QSCALE;

    __shared__ __align__(16) __bf16 As[128 * 32];
    __shared__ __align__(16) __bf16 Bs[128 * 32];

    const int tid  = threadIdx.x;
    const int lane = tid & 63;
    const int wave = tid >> 6;
    const int wm = (wave >> 1) * 64;
    const int wn = (wave & 1) * 64;
    const int c16 = lane & 15;
    const int g8  = (lane >> 4) * 8;
    const int row0 = blockIdx.x * 128;
    const int col0 = blockIdx.y * 128;
    const int brow = tid >> 1;
    const int bcc  = (tid & 1) * 16;

    f32x4 acc[4][4] = {};
    for (int k0 = 0; k0 < DM; k0 += 32) {
        __syncthreads();
        #pragma unroll
        for (int h = 0; h < 2; h++) {
            int cidx = h * 256 + tid;
            gl_lds16(&X[(size_t)(row0 + (cidx >> 2)) * DM + k0 + (cidx & 3) * 8],
                     &As[(size_t)(h * 256 + wave * 64) * 8]);
        }
        *(bf16x8*)&Bs[brow * 32 + bcc]     = cvt8(&W[(size_t)(col0 + brow) * DM + k0 + bcc]);
        *(bf16x8*)&Bs[brow * 32 + bcc + 8] = cvt8(&W[(size_t)(col0 + brow) * DM + k0 + bcc + 8]);
        __syncthreads();

        bf16x8 a[4], bfr[4];
        #pragma unroll
        for (int i = 0; i < 4; i++) a[i]   = *(const bf16x8*)&As[(wm + i * 16 + c16) * 32 + g8];
        #pragma unroll
        for (int i = 0; i < 4; i++) bfr[i] = *(const bf16x8*)&Bs[(wn + i * 16 + c16) * 32 + g8];
        #pragma unroll
        for (int mi = 0; mi < 4; mi++)
            #pragma unroll
            for (int ni = 0; ni < 4; ni++)
                acc[mi][ni] = __builtin_amdgcn_mfma_f32_16x16x32_bf16(a[mi], bfr[ni], acc[mi][ni], 0, 0, 0);
    }

    #pragma unroll
    for (int mi = 0; mi < 4; mi++) {
        int r0 = row0 + wm + mi * 16 + (lane >> 4) * 4;
        #pragma unroll
        for (int ni = 0; ni < 4; ni++) {
            int col = col0 + wn + ni * 16 + c16;
            float bsv = bias[col];
            int h = col >> 6, d = col & 63;
            #pragma unroll
            for (int i = 0; i < 4; i++) {
                int r = r0 + i; int b = r >> 11, s = r & 2047;
                O[((size_t)(b * NH + h) * SEQ + s) * HD + d] = (__bf16)((acc[mi][ni][i] + bsv) * qsc);
            }
        }
    }
}

__global__ __launch_bounds__(256) void gemm_v(
    const float* __restrict__ vf, const float* __restrict__ wvf,
    const float* __restrict__ bv, __bf16* __restrict__ Vt)
{
    __shared__ __align__(16) __bf16 As[128 * 32];
    __shared__ __align__(16) __bf16 Bs[128 * 32];

    const int tid  = threadIdx.x;
    const int lane = tid & 63;
    const int wave = tid >> 6;
    const int wm = (wave >> 1) * 64;
    const int wn = (wave & 1) * 64;
    const int c16 = lane & 15;
    const int g8  = (lane >> 4) * 8;
    const int row0 = blockIdx.x * 128;
    const int col0 = blockIdx.y * 128;
    const int brow = tid >> 1;
    const int bcc  = (tid & 1) * 16;

    f32x4 acc[4][4] = {};
    for (int k0 = 0; k0 < DM; k0 += 32) {
        __syncthreads();
        *(bf16x8*)&As[brow * 32 + bcc]     = cvt8(&vf[(size_t)(row0 + brow) * DM + k0 + bcc]);
        *(bf16x8*)&As[brow * 32 + bcc + 8] = cvt8(&vf[(size_t)(row0 + brow) * DM + k0 + bcc + 8]);
        *(bf16x8*)&Bs[brow * 32 + bcc]     = cvt8(&wvf[(size_t)(col0 + brow) * DM + k0 + bcc]);
        *(bf16x8*)&Bs[brow * 32 + bcc + 8] = cvt8(&wvf[(size_t)(col0 + brow) * DM + k0 + bcc + 8]);
        __syncthreads();

        bf16x8 a[4], bfr[4];
        #pragma unroll
        for (int i = 0; i < 4; i++) a[i]   = *(const bf16x8*)&As[(wm + i * 16 + c16) * 32 + g8];
        #pragma unroll
        for (int i = 0; i < 4; i++) bfr[i] = *(const bf16x8*)&Bs[(wn + i * 16 + c16) * 32 + g8];
        #pragma unroll
        for (int mi = 0; mi < 4; mi++)
            #pragma unroll
            for (int ni = 0; ni < 4; ni++)
                acc[mi][ni] = __builtin_amdgcn_mfma_f32_16x16x32_bf16(a[mi], bfr[ni], acc[mi][ni], 0, 0, 0);
    }

    #pragma unroll
    for (int mi = 0; mi < 4; mi++) {
        int r0 = row0 + wm + mi * 16 + (lane >> 4) * 4;
        #pragma unroll
        for (int ni = 0; ni < 4; ni++) {
            int col = col0 + wn + ni * 16 + c16;
            float bsv = bv[col];
            int h = col >> 6, d = col & 63;
            int b = r0 >> 11, s0 = r0 & 2047;
            size_t base = ((size_t)((b * NH + h) * HD + d)) * SEQ + s0;
            #pragma unroll
            for (int i = 0; i < 4; i++)
                Vt[base + i] = (__bf16)(acc[mi][ni][i] + bsv);
        }
    }
}

__global__ __launch_bounds__(256) void gemm_fc(
    const __bf16* __restrict__ Xc, const float* __restrict__ Wf,
    const float* __restrict__ bias, float* __restrict__ out)
{
    __shared__ __align__(16) __bf16 As[128 * 32];
    __shared__ __align__(16) __bf16 Bs[128 * 32];

    const int tid  = threadIdx.x;
    const int lane = tid & 63;
    const int wave = tid >> 6;
    const int wm = (wave >> 1) * 64;
    const int wn = (wave & 1) * 64;
    const int c16 = lane & 15;
    const int g8  = (lane >> 4) * 8;
    const int row0 = blockIdx.x * 128;
    const int col0 = blockIdx.y * 128;
    const int brow = tid >> 1;
    const int bcc  = (tid & 1) * 16;

    f32x4 acc[4][4] = {};
    for (int k0 = 0; k0 < DM; k0 += 32) {
        __syncthreads();
        #pragma unroll
        for (int h = 0; h < 2; h++) {
            int cidx = h * 256 + tid;
            gl_lds16(&Xc[(size_t)(row0 + (cidx >> 2)) * DM + k0 + (cidx & 3) * 8],
                     &As[(size_t)(h * 256 + wave * 64) * 8]);
        }
        *(bf16x8*)&Bs[brow * 32 + bcc]     = cvt8(&Wf[(size_t)(col0 + brow) * DM + k0 + bcc]);
        *(bf16x8*)&Bs[brow * 32 + bcc + 8] = cvt8(&Wf[(size_t)(col0 + brow) * DM + k0 + bcc + 8]);
        __syncthreads();

        bf16x8 a[4], bfr[4];
        #pragma unroll
        for (int i = 0; i < 4; i++) a[i]   = *(const bf16x8*)&As[(wm + i * 16 + c16) * 32 + g8];
        #pragma unroll
        for (int i = 0; i < 4; i++) bfr[i] = *(const bf16x8*)&Bs[(wn + i * 16 + c16) * 32 + g8];
        #pragma unroll
        for (int mi = 0; mi < 4; mi++)
            #pragma unroll
            for (int ni = 0; ni < 4; ni++)
                acc[mi][ni] = __builtin_amdgcn_mfma_f32_16x16x32_bf16(a[mi], bfr[ni], acc[mi][ni], 0, 0, 0);
    }

    #pragma unroll
    for (int mi = 0; mi < 4; mi++) {
        int r0 = row0 + wm + mi * 16 + (lane >> 4) * 4;
        #pragma unroll
        for (int ni = 0; ni < 4; ni++) {
            int col = col0 + wn + ni * 16 + c16;
            float bsv = bias[col];
            #pragma unroll
            for (int i = 0; i < 4; i++)
                out[(size_t)(r0 + i) * DM + col] = acc[mi][ni][i] + bsv;
        }
    }
}

// ======================================================================
// flash attention (R9 proven structure: 16x16 MFMA, 4-wave, QSCALE fold,
// transposed grid, permuted-k PV contract, 16KB LDS, single-buffered)
// + ONES-MFMA l-SUM: the softmax denominator is computed on the MATRIX
// pipe instead of the VALU. With A = all-ones bf16 fragment,
//   mfma(ones, pf[qs][kc], la[qs]) gives D[m][q] = sum_k P[q][k] for
// the 32 keys of chunk kc (every row m identical). Accumulated over
// kc and tiles, la[qs][0] = full denominator for query q=c16 — removes
// 32 VALU adds/tile/wave AND the end-of-kernel cross-lane reduce.
// (R14 evidence: throughput invariant to occupancy => issue-bound on
// VALU+MFMA; this trades 4 MFMA/tile for ~64 VALU cyc/tile.)
// grid (B*H, SEQ/128), block 256 = 4 waves; wave owns 32 queries.
// ======================================================================
__global__ __launch_bounds__(256, 4) void attn_kernel(
    const __bf16* __restrict__ Qp, const __bf16* __restrict__ Kp,
    const __bf16* __restrict__ Vt, __bf16* __restrict__ ctx)
{
    __shared__ __align__(16) __bf16 Ks[64 * 64];        // [key][d], swizzled
    __shared__ __align__(16) __bf16 Vs[64 * 64];        // [d][key], swizzled

    const int tid  = threadIdx.x;
    const int lane = tid & 63;
    const int w    = tid >> 6;
    const int bh   = blockIdx.x;                        // head index (XCD-local)
    const int q0   = blockIdx.y * 128 + w * 32;

    const __bf16* Qb = Qp + (size_t)bh * SEQ * HD;
    const __bf16* Kb = Kp + (size_t)bh * SEQ * HD;
    const __bf16* Vb = Vt + (size_t)bh * HD * SEQ;

    const int c16 = lane & 15;
    const int g   = lane >> 4;
    const int sw  = c16 & 7;    // swizzle key for this lane's frag rows

    // Q as B-fragment of Q^T: lane holds Q[query=c16][k = kc*32 + g*8 + j]
    bf16x8 qf[2][2];
    #pragma unroll
    for (int qs = 0; qs < 2; qs++)
        #pragma unroll
        for (int kc = 0; kc < 2; kc++)
            qf[qs][kc] = *(const bf16x8*)&Qb[(size_t)(q0 + qs * 16 + c16) * HD + kc * 32 + g * 8];

    // all-ones A fragment for the l-sum MFMA
    bf16x8 ones;
    #pragma unroll
    for (int i = 0; i < 8; i++) ones[i] = (__bf16)1.0f;

    f32x4 o[4][2] = {};                 // O^T: row d = t*16+g*4+i, col query = c16
    f32x4 la[2] = {};                   // l accumulators (all rows identical)

    // GLDS staging: wave w stages rows w*16 .. w*16+15 of Ks and Vs.
    const int srow = (w * 16) + (lane >> 3);          // +8 for h=1
    const int sj   = (lane & 7) ^ (lane >> 3);        // logical chunk (XOR swizzle)

    for (int kt = 0; kt < SEQ / 64; kt++) {
        const int k0 = kt * 64;
        __syncthreads();
        #pragma unroll
        for (int h = 0; h < 2; h++) {
            int r = srow + h * 8;
            gl_lds16(&Kb[(size_t)(k0 + r) * HD + sj * 8], &Ks[(size_t)(w * 16 + h * 8) * 64]);
            gl_lds16(&Vb[(size_t)r * SEQ + k0 + sj * 8],  &Vs[(size_t)(w * 16 + h * 8) * 64]);
        }
        __syncthreads();

        // S^T = K · Q^T : rows = keys, cols = queries
        f32x4 sc[4][2] = {};
        #pragma unroll
        for (int t = 0; t < 4; t++) {
            #pragma unroll
            for (int kc = 0; kc < 2; kc++) {
                bf16x8 kf = *(const bf16x8*)&Ks[(t * 16 + c16) * 64 + ((kc * 4 + g) ^ sw) * 8];
                sc[t][0] = __builtin_amdgcn_mfma_f32_16x16x32_bf16(kf, qf[0][kc], sc[t][0], 0, 0, 0);
                sc[t][1] = __builtin_amdgcn_mfma_f32_16x16x32_bf16(kf, qf[1][kc], sc[t][1], 0, 0, 0);
            }
        }

        // softmax + permuted-k B-frag pack, fully in-register:
        // pf[qs][kc][j] = exp2(sc[2kc + (j>=4)][qs][j&3]); NO VALU l-sum.
        bf16x8 pf[2][2];
        #pragma unroll
        for (int qs = 0; qs < 2; qs++) {
            #pragma unroll
            for (int kc = 0; kc < 2; kc++) {
                bf16x8 pv8;
                #pragma unroll
                for (int i = 0; i < 4; i++)
                    pv8[i] = (__bf16)exp2f(sc[2 * kc][qs][i]);
                #pragma unroll
                for (int i = 0; i < 4; i++)
                    pv8[4 + i] = (__bf16)exp2f(sc[2 * kc + 1][qs][i]);
                pf[qs][kc] = pv8;
            }
        }

        // l-sum on the matrix pipe: la[qs] += ones · pf[qs][kc]
        #pragma unroll
        for (int kc = 0; kc < 2; kc++) {
            la[0] = __builtin_amdgcn_mfma_f32_16x16x32_bf16(ones, pf[0][kc], la[0], 0, 0, 0);
            la[1] = __builtin_amdgcn_mfma_f32_16x16x32_bf16(ones, pf[1][kc], la[1], 0, 0, 0);
        }

        // O^T += V^T · P^T with permuted-k A reads:
        // slot (g, j<4)  -> key kc*32 + 4g + j    (chunk kc*4+(g>>1),   elem (g&1)*4)
        // slot (g, j>=4) -> key kc*32 + 16+4g+j-4 (chunk kc*4+2+(g>>1), elem (g&1)*4)
        #pragma unroll
        for (int t = 0; t < 4; t++) {
            #pragma unroll
            for (int kc = 0; kc < 2; kc++) {
                union { bf16x8 v8; bf16x4 v4[2]; } u;
                u.v4[0] = *(const bf16x4*)&Vs[(t * 16 + c16) * 64 + (((kc * 4 + (g >> 1)) ^ sw) * 8) + (g & 1) * 4];
                u.v4[1] = *(const bf16x4*)&Vs[(t * 16 + c16) * 64 + (((kc * 4 + 2 + (g >> 1)) ^ sw) * 8) + (g & 1) * 4];
                o[t][0] = __builtin_amdgcn_mfma_f32_16x16x32_bf16(u.v8, pf[0][kc], o[t][0], 0, 0, 0);
                o[t][1] = __builtin_amdgcn_mfma_f32_16x16x32_bf16(u.v8, pf[1][kc], o[t][1], 0, 0, 0);
            }
        }
    }

    // finalize: l comes straight from the MFMA accumulator (no reduce)
    const int hh = bh & (NH - 1);
    const int bb = bh >> 4;
    #pragma unroll
    for (int qs = 0; qs < 2; qs++) {
        float inv = 1.f / la[qs][0];
        int s = q0 + qs * 16 + c16;
        #pragma unroll
        for (int t = 0; t < 4; t++) {
            bf16x4 ov;
            #pragma unroll
            for (int i = 0; i < 4; i++) ov[i] = (__bf16)(o[t][qs][i] * inv);
            *(bf16x4*)&ctx[((size_t)(bb * SEQ + s)) * DM + hh * HD + t * 16 + g * 4] = ov;
        }
    }
}

// ---------------- launch ----------------
extern "C" void kernel_launch(void* const* d_in, const int* in_sizes, int n_in,
                              void* d_out, int out_size, void* d_ws, size_t ws_size,
                              hipStream_t stream) {
    const float* q    = (const float*)d_in[0];
    const float* k    = (const float*)d_in[1];
    const float* v    = (const float*)d_in[2];
    const float* w_q  = (const float*)d_in[3];
    const float* b_q  = (const float*)d_in[4];
    const float* w_k  = (const float*)d_in[5];
    const float* b_k  = (const float*)d_in[6];
    const float* w_v  = (const float*)d_in[7];
    const float* b_v  = (const float*)d_in[8];
    const float* w_fc = (const float*)d_in[9];
    const float* b_fc = (const float*)d_in[10];
    float* out = (float*)d_out;

    // qb,kb live in d_out (dead before gemm_fc writes it)
    __bf16* qb = (__bf16*)d_out;
    __bf16* kb = qb + (size_t)ROWS * DM;

    char* p = (char*)d_ws;
    auto alloc = [&](size_t bytes) { char* r = p; p += (bytes + 255) & ~(size_t)255; return r; };
    const size_t XSZ = (size_t)ROWS * DM * 2;   // 16.78 MB
    const size_t WSZ = (size_t)DM * DM * 2;     // 2.10 MB

    __bf16* Qp  = (__bf16*)alloc(XSZ);
    __bf16* Kp  = (__bf16*)alloc(XSZ);
    __bf16* Vt  = (__bf16*)alloc(XSZ);
    __bf16* ctx = (__bf16*)alloc(XSZ);

    const size_t base_need = (size_t)(p - (char*)d_ws);
    const size_t fast_need = base_need + 4 * (WSZ + 256);

    const int n8x = ROWS * DM / 8;   // 1,048,576
    const int n8w = DM * DM / 8;     // 131,072

    // vb lives in the ctx region: dead before attn writes ctx, and does NOT
    // alias Qp -> enables the single merged QKV projection launch.
    __bf16* vb = ctx;

    // q,k -> d_out region; v -> ctx region (one merged launch)
    cast3<<<dim3(n8x / 256, 3), 256, 0, stream>>>(q, k, v, qb, kb, vb, n8x);

    if (ws_size >= fast_need) {
        // FAST PATH: bf16 weights in ws, all GEMMs all-GLDS.
        __bf16* wqb  = (__bf16*)alloc(WSZ);
        __bf16* wkb  = (__bf16*)alloc(WSZ);
        __bf16* wvb  = (__bf16*)alloc(WSZ);
        __bf16* wfcb = (__bf16*)alloc(WSZ);

        cast4<<<dim3(n8w / 256, 4), 256, 0, stream>>>(
            w_q, w_k, w_v, w_fc, wqb, wkb, wvb, wfcb, n8w);

        // merged Q/K/V projections: one 1536-block launch (6 blocks/CU)
        gemm_qkv_f<<<dim3(ROWS / 128, DM / 128, 3), 256, 0, stream>>>(
            qb, kb, vb, wqb, wkb, wvb, b_q, b_k, b_v, Qp, Kp, Vt);

        // grid: x = head (XCD-local K/V), y = q-block (128 queries)
        attn_kernel<<<dim3(BN * NH, SEQ / 128), 256, 0, stream>>>(Qp, Kp, Vt, ctx);

        // FC: 128x64 tiles -> 1024 blocks (4/CU)
        gemm_fc_f<<<dim3(ROWS / 128, DM / 64), 256, 0, stream>>>(ctx, wfcb, b_fc, out);
    } else {
        // FALLBACK (67 MB ws)
        gemm_v<<<dim3(ROWS / 128, DM / 128), 256, 0, stream>>>(v, w_v, b_v, Vt);
        gemm_qk<<<dim3(ROWS / 128, DM / 128, 2), 256, 0, stream>>>(
            qb, kb, w_q, w_k, b_q, b_k, Qp, Kp);

        attn_kernel<<<dim3(BN * NH, SEQ / 128), 256, 0, stream>>>(Qp, Kp, Vt, ctx);

        gemm_fc<<<dim3(ROWS / 128, DM / 128), 256, 0, stream>>>(ctx, w_fc, b_fc, out);
    }
}